// Round 2
// baseline (394.449 us; speedup 1.0000x reference)
//
#include <hip/hip_runtime.h>
#include <math.h>

#define NROWS    16384
#define NBOOKS   128
#define NWORDS   64
#define LWORD    32
#define TILE_N   256
#define DIMS     (NBOOKS * LWORD)          /* 4096 */
#define TAU_K    14.4269504088896340736f   /* 10 * log2(e) */
#define Z_ELEMS  67108864ull               /* 16384*4096 */

/* numpy pairwise-sum replica for n=32 f32 (8 accumulators, exact order,
   contraction off so no mul+add fusion changes rounding). */
__device__ __forceinline__ float np_sum32(const float* a) {
#pragma clang fp contract(off)
    float r0 = a[0], r1 = a[1], r2 = a[2], r3 = a[3];
    float r4 = a[4], r5 = a[5], r6 = a[6], r7 = a[7];
    r0 += a[8];  r1 += a[9];  r2 += a[10]; r3 += a[11];
    r4 += a[12]; r5 += a[13]; r6 += a[14]; r7 += a[15];
    r0 += a[16]; r1 += a[17]; r2 += a[18]; r3 += a[19];
    r4 += a[20]; r5 += a[21]; r6 += a[22]; r7 += a[23];
    r0 += a[24]; r1 += a[25]; r2 += a[26]; r3 += a[27];
    r4 += a[28]; r5 += a[29]; r6 += a[30]; r7 += a[31];
    return ((r0 + r1) + (r2 + r3)) + ((r4 + r5) + (r6 + r7));
}

/* ---------- kernel 1: np-exact per-book L2-normalize of codewords ---------- */
__global__ __launch_bounds__(256) void normC_kernel(const float* __restrict__ C,
                                                    float* __restrict__ cbT,
                                                    float* __restrict__ c2T) {
#pragma clang fp contract(off)
    int t = blockIdx.x * 256 + threadIdx.x;    /* 0..8191 = one (w,b) */
    int w = t & (NWORDS - 1);
    int b = t >> 6;
    const float* src = C + (size_t)w * DIMS + b * LWORD;
    float v[LWORD];
    #pragma unroll
    for (int q = 0; q < 8; ++q)
        *(float4*)&v[4 * q] = *(const float4*)&src[4 * q];
    float sq[LWORD];
    #pragma unroll
    for (int l = 0; l < LWORD; ++l) sq[l] = v[l] * v[l];
    float nrm = fmaxf(sqrtf(np_sum32(sq)), 1e-12f);
    float cb[LWORD];
    #pragma unroll
    for (int l = 0; l < LWORD; ++l) cb[l] = v[l] / nrm;   /* IEEE f32 div */
    float sq2[LWORD];
    #pragma unroll
    for (int l = 0; l < LWORD; ++l) sq2[l] = cb[l] * cb[l];
    float c2 = np_sum32(sq2);
    float* dst = cbT + ((size_t)b * NWORDS + w) * LWORD;
    #pragma unroll
    for (int q = 0; q < 8; ++q)
        *(float4*)&dst[4 * q] = *(const float4*)&cb[4 * q];
    c2T[b * NWORDS + w] = c2;
}

/* ---------- kernel 2: fused dist + online softmax + Z + argmin ---------- */
__global__ __launch_bounds__(256, 3) void softpq_kernel(const float* __restrict__ x,
                                                        const float* __restrict__ cbT,
                                                        const float* __restrict__ c2T,
                                                        float* __restrict__ out) {
    __shared__ float cb_s[NWORDS][LWORD];       /* 8 KB, wave-uniform: broadcast */
    __shared__ float c2_s[NWORDS];
    __shared__ float x_s[TILE_N][LWORD + 1];    /* +1 pad: conflict-free         */

    int u = blockIdx.x;                          /* XCD-chunked remap */
    int logical = (u & 7) * 1024 + (u >> 3);
    int b    = logical & (NBOOKS - 1);
    int tile = logical >> 7;
    int n0   = tile * TILE_N;
    int t    = threadIdx.x;

    {   /* stage codebook */
        const float4* src = (const float4*)(cbT + (size_t)b * (NWORDS * LWORD));
        float4* dst = (float4*)&cb_s[0][0];
        dst[t]       = src[t];
        dst[t + 256] = src[t + 256];
        if (t < NWORDS) c2_s[t] = c2T[b * NWORDS + t];
    }
    #pragma unroll
    for (int r = 0; r < 8; ++r) {               /* stage x tile, coalesced */
        int id  = t + r * 256;
        int row = id >> 3;
        int c4  = id & 7;
        float4 v = *(const float4*)(x + (size_t)(n0 + row) * DIMS + b * LWORD + c4 * 4);
        x_s[row][c4 * 4 + 0] = v.x;
        x_s[row][c4 * 4 + 1] = v.y;
        x_s[row][c4 * 4 + 2] = v.z;
        x_s[row][c4 * 4 + 3] = v.w;
    }
    __syncthreads();

    float xr[LWORD];
    #pragma unroll
    for (int l = 0; l < LWORD; ++l) xr[l] = x_s[t][l];
    float a0 = 0.f, a1 = 0.f, a2 = 0.f, a3 = 0.f;
    #pragma unroll
    for (int l = 0; l < 8; ++l) {
        a0 = fmaf(xr[l],      xr[l],      a0);
        a1 = fmaf(xr[l + 8],  xr[l + 8],  a1);
        a2 = fmaf(xr[l + 16], xr[l + 16], a2);
        a3 = fmaf(xr[l + 24], xr[l + 24], a3);
    }
    float x2 = (a0 + a1) + (a2 + a3);

    float z[LWORD];
    #pragma unroll
    for (int l = 0; l < LWORD; ++l) z[l] = 0.f;
    float sum  = 0.f;
    float m1   = __builtin_inff();
    float m2   = __builtin_inff();
    float mref = __builtin_inff();
    int   wmin = 0;

    #pragma unroll 2
    for (int w = 0; w < NWORDS; ++w) {
        float cq[LWORD];
        #pragma unroll
        for (int q = 0; q < 8; ++q)
            *(float4*)&cq[4 * q] = *((const float4*)&cb_s[w][0] + q);
        float c2w = c2_s[w];

        float d0 = 0.f, d1 = 0.f, d2 = 0.f, d3 = 0.f;
        #pragma unroll
        for (int l = 0; l < 8; ++l) {
            d0 = fmaf(xr[l],      cq[l],      d0);
            d1 = fmaf(xr[l + 8],  cq[l + 8],  d1);
            d2 = fmaf(xr[l + 16], cq[l + 16], d2);
            d3 = fmaf(xr[l + 24], cq[l + 24], d3);
        }
        float dot = (d0 + d1) + (d2 + d3);
        float d   = fmaf(-2.0f, dot, x2 + c2w);

        bool lt = d < m1;
        m2 = fminf(m2, fmaxf(d, m1));
        if (lt) wmin = w;
        m1 = fminf(m1, d);
        if (mref - m1 > 2.0f) {
            float f = __builtin_amdgcn_exp2f((m1 - mref) * TAU_K);
            sum *= f;
            #pragma unroll
            for (int l = 0; l < LWORD; ++l) z[l] *= f;
            mref = m1;
        }
        float p = __builtin_amdgcn_exp2f((mref - d) * TAU_K);
        sum += p;
        #pragma unroll
        for (int l = 0; l < LWORD; ++l) z[l] = fmaf(p, cq[l], z[l]);
    }

    /* near-tie rows (~350 of 2.1M): replicate the numpy-f32 reference exactly.
       x2/c2 use np pairwise order; xc via f64 (correctly-rounded truth);
       dist = fl(fl(x2+c2) - fl(2*xc)); first-min tie rule. */
    if (m2 - m1 < 1e-4f) {
        float sq[LWORD];
        #pragma unroll
        for (int l = 0; l < LWORD; ++l) sq[l] = xr[l] * xr[l];
        float x2n = np_sum32(sq);
        float best = __builtin_inff();
        int wbest = 0;
        for (int w2 = 0; w2 < NWORDS; ++w2) {
            double acc = 0.0;
            #pragma unroll
            for (int l = 0; l < LWORD; ++l)
                acc = fma((double)xr[l], (double)cb_s[w2][l], acc);
            float xcf = (float)acc;
            float dnp;
            {
#pragma clang fp contract(off)
                float s1 = x2n + c2_s[w2];
                float s2 = 2.0f * xcf;
                dnp = s1 - s2;
            }
            if (dnp < best) { best = dnp; wbest = w2; }
        }
        wmin = wbest;
    }

    float inv = 1.0f / sum;
    __syncthreads();
    #pragma unroll
    for (int l = 0; l < LWORD; ++l) x_s[t][l] = z[l] * inv;
    __syncthreads();
    #pragma unroll
    for (int r = 0; r < 8; ++r) {
        int id  = t + r * 256;
        int row = id >> 3;
        int c4  = id & 7;
        float4 v;
        v.x = x_s[row][c4 * 4 + 0];
        v.y = x_s[row][c4 * 4 + 1];
        v.z = x_s[row][c4 * 4 + 2];
        v.w = x_s[row][c4 * 4 + 3];
        *(float4*)(out + (size_t)(n0 + row) * DIMS + b * LWORD + c4 * 4) = v;
    }
    out[Z_ELEMS + (size_t)(n0 + t) * NBOOKS + b] = (float)wmin;
}

extern "C" void kernel_launch(void* const* d_in, const int* in_sizes, int n_in,
                              void* d_out, int out_size, void* d_ws, size_t ws_size,
                              hipStream_t stream) {
    const float* x = (const float*)d_in[0];
    const float* C = (const float*)d_in[1];
    float* out = (float*)d_out;
    float* cbT = (float*)d_ws;                               /* 1 MB   */
    float* c2T = cbT + (size_t)NBOOKS * NWORDS * LWORD;      /* +32 KB */

    normC_kernel<<<32, 256, 0, stream>>>(C, cbT, c2T);
    softpq_kernel<<<8192, 256, 0, stream>>>(x, cbT, c2T, out);
}

// Round 3
// 239.428 us; speedup vs baseline: 1.6475x; 1.6475x over previous
//
#include <hip/hip_runtime.h>
#include <math.h>

#define NROWS   16384
#define NBOOKS  128
#define NWORDS  64
#define LWORD   32
#define DIMS    4096
#define TAU_K   14.4269504088896340736f   /* 10 * log2(e) */
#define Z_ELEMS 67108864ull               /* 16384*4096 */

typedef __attribute__((ext_vector_type(8))) short s16x8;
typedef __attribute__((ext_vector_type(4))) float f32x4;

/* ws layout (bytes) */
#define CBT_OFF  0u           /* f32 [128][64][32] np-normalized codewords */
#define C2T_OFF  1048576u     /* f32 [128][64]                             */
#define CHA_OFF  1081344u     /* bf16 S-frags hi: [(b*4+wb)*64+lane][8]    */
#define CLA_OFF  1605632u     /* bf16 S-frags lo                           */
#define A2_OFF   2129920u     /* bf16 Z-frags:   [(b*4+mb*2+kc)*64+lane][8]*/

__device__ __forceinline__ unsigned short f2bf(float f) {
    unsigned int u = __float_as_uint(f);
    unsigned int r = (u + 0x7FFFu + ((u >> 16) & 1u)) >> 16;   /* RNE */
    return (unsigned short)r;
}
__device__ __forceinline__ float bf2f(unsigned short s) {
    return __uint_as_float(((unsigned int)s) << 16);
}

/* numpy pairwise-sum replica for n=32 f32 (exact order, no contraction) */
__device__ __forceinline__ float np_sum32(const float* a) {
#pragma clang fp contract(off)
    float r0 = a[0], r1 = a[1], r2 = a[2], r3 = a[3];
    float r4 = a[4], r5 = a[5], r6 = a[6], r7 = a[7];
    r0 += a[8];  r1 += a[9];  r2 += a[10]; r3 += a[11];
    r4 += a[12]; r5 += a[13]; r6 += a[14]; r7 += a[15];
    r0 += a[16]; r1 += a[17]; r2 += a[18]; r3 += a[19];
    r4 += a[20]; r5 += a[21]; r6 += a[22]; r7 += a[23];
    r0 += a[24]; r1 += a[25]; r2 += a[26]; r3 += a[27];
    r4 += a[28]; r5 += a[29]; r6 += a[30]; r7 += a[31];
    return ((r0 + r1) + (r2 + r3)) + ((r4 + r5) + (r6 + r7));
}

/* ---------- kernel 1: np-exact per-book L2-normalize (unchanged, verified) ---------- */
__global__ __launch_bounds__(256) void normC_kernel(const float* __restrict__ C,
                                                    float* __restrict__ cbT,
                                                    float* __restrict__ c2T) {
#pragma clang fp contract(off)
    int t = blockIdx.x * 256 + threadIdx.x;
    int w = t & (NWORDS - 1);
    int b = t >> 6;
    const float* src = C + (size_t)w * DIMS + b * LWORD;
    float v[LWORD];
    #pragma unroll
    for (int q = 0; q < 8; ++q)
        *(float4*)&v[4 * q] = *(const float4*)&src[4 * q];
    float sq[LWORD];
    #pragma unroll
    for (int l = 0; l < LWORD; ++l) sq[l] = v[l] * v[l];
    float nrm = fmaxf(sqrtf(np_sum32(sq)), 1e-12f);
    float cb[LWORD];
    #pragma unroll
    for (int l = 0; l < LWORD; ++l) cb[l] = v[l] / nrm;
    float sq2[LWORD];
    #pragma unroll
    for (int l = 0; l < LWORD; ++l) sq2[l] = cb[l] * cb[l];
    float c2 = np_sum32(sq2);
    float* dst = cbT + ((size_t)b * NWORDS + w) * LWORD;
    #pragma unroll
    for (int q = 0; q < 8; ++q)
        *(float4*)&dst[4 * q] = *(const float4*)&cb[4 * q];
    c2T[b * NWORDS + w] = c2;
}

/* ---------- kernel 1b: build MFMA fragment-layout codeword arrays ---------- */
__global__ __launch_bounds__(64) void fragC_kernel(const float* __restrict__ cbT,
                                                   unsigned short* __restrict__ chA,
                                                   unsigned short* __restrict__ clA,
                                                   unsigned short* __restrict__ a2A) {
    int b = blockIdx.x;
    int l = threadIdx.x;
    int lr = l & 15, lh = l >> 4;
    /* S-GEMM A-frags: A[word=16wb+lr][dim=8*lh+i], split hi/lo bf16 */
    #pragma unroll
    for (int wb = 0; wb < 4; ++wb) {
        size_t base = ((size_t)(b * 4 + wb) * 64 + l) * 8;
        #pragma unroll
        for (int i = 0; i < 8; ++i) {
            float f = cbT[((size_t)b * NWORDS + (wb * 16 + lr)) * LWORD + (lh * 8 + i)];
            unsigned short h = f2bf(f);
            chA[base + i] = h;
            clA[base + i] = f2bf(f - bf2f(h));
        }
    }
    /* Z-GEMM A-frags: A[dim=16mb+lr][word=32kc+8*lh+i], bf16 hi only */
    #pragma unroll
    for (int mb = 0; mb < 2; ++mb)
        #pragma unroll
        for (int kc = 0; kc < 2; ++kc) {
            size_t base = ((size_t)(b * 4 + mb * 2 + kc) * 64 + l) * 8;
            #pragma unroll
            for (int i = 0; i < 8; ++i)
                a2A[base + i] =
                    f2bf(cbT[((size_t)b * NWORDS + (kc * 32 + lh * 8 + i)) * LWORD + (mb * 16 + lr)]);
        }
}

/* ---------- kernel 2: MFMA dist + softmax + Z + argmin ---------- */
__global__ __launch_bounds__(256, 4) void softpq_mfma(const float* __restrict__ x,
                                                      const float* __restrict__ cbT,
                                                      const float* __restrict__ c2T,
                                                      const unsigned short* __restrict__ chA,
                                                      const unsigned short* __restrict__ clA,
                                                      const unsigned short* __restrict__ a2A,
                                                      float* __restrict__ out) {
    __shared__ float x_s[64][36];                      /* 9216 B, +4 pad: 16B-aligned rows */
    __shared__ __align__(16) unsigned short ps_s[4][16][72];  /* per-wave P, 9216 B        */
    __shared__ float c2_s[NWORDS];

    /* XCD-chunked: each XCD owns 16 books x 256 tiles -> codeword frags L2-resident */
    int u = blockIdx.x;
    int L = (u & 7) * 4096 + (u >> 3);
    int b    = L >> 8;
    int tile = L & 255;
    int n0 = tile * 64;
    int t  = threadIdx.x;
    int lane = t & 63, wid = t >> 6;
    int h = lane >> 4, c = lane & 15;
    int R = wid * 16 + c;                              /* this lane's row in the tile */

    /* early: stream S-frags (coalesced 16B/lane, L2-hot) */
    const s16x8* chp = (const s16x8*)chA;
    const s16x8* clp = (const s16x8*)clA;
    s16x8 chf[4], clf[4];
    #pragma unroll
    for (int wb = 0; wb < 4; ++wb) {
        chf[wb] = chp[(size_t)(b * 4 + wb) * 64 + lane];
        clf[wb] = clp[(size_t)(b * 4 + wb) * 64 + lane];
    }

    /* stage x tile (64 rows x 128B) + c2 */
    {
        int row = t >> 2, q = t & 3;
        const float* src = x + (size_t)(n0 + row) * DIMS + b * LWORD + q * 8;
        float4 v0 = *(const float4*)src;
        float4 v1 = *(const float4*)(src + 4);
        *(float4*)&x_s[row][q * 8]     = v0;
        *(float4*)&x_s[row][q * 8 + 4] = v1;
    }
    if (t < NWORDS) c2_s[t] = c2T[b * NWORDS + t];
    __syncthreads();

    /* x B-frag (row=c, dims 8h..8h+7) + split + x2 partial */
    float xf[8];
    *(float4*)&xf[0] = *(const float4*)&x_s[R][h * 8];
    *(float4*)&xf[4] = *(const float4*)&x_s[R][h * 8 + 4];
    s16x8 xh, xl;
    float x2p = 0.f;
    #pragma unroll
    for (int i = 0; i < 8; ++i) {
        unsigned short hh = f2bf(xf[i]);
        xh[i] = (short)hh;
        xl[i] = (short)f2bf(xf[i] - bf2f(hh));
        x2p = fmaf(xf[i], xf[i], x2p);
    }
    x2p += __shfl_xor(x2p, 16);
    x2p += __shfl_xor(x2p, 32);
    float x2 = x2p;

    /* 12 S-MFMAs: dot[word][row] ~ xh.ch + xl.ch + xh.cl */
    f32x4 acc[4];
    #pragma unroll
    for (int wb = 0; wb < 4; ++wb) {
        f32x4 a = {0.f, 0.f, 0.f, 0.f};
        a = __builtin_amdgcn_mfma_f32_16x16x32_bf16(chf[wb], xh, a, 0, 0, 0);
        a = __builtin_amdgcn_mfma_f32_16x16x32_bf16(chf[wb], xl, a, 0, 0, 0);
        a = __builtin_amdgcn_mfma_f32_16x16x32_bf16(clf[wb], xh, a, 0, 0, 0);
        acc[wb] = a;
    }

    /* Z-frags now (hide latency under softmax VALU) */
    const s16x8* a2p = (const s16x8*)a2A;
    s16x8 a2f[4];
    #pragma unroll
    for (int q = 0; q < 4; ++q)
        a2f[q] = a2p[(size_t)(b * 4 + q) * 64 + lane];

    /* d[i]: word = wb*16 + h*4 + r for this lane's row c */
    float d[16];
    #pragma unroll
    for (int wb = 0; wb < 4; ++wb)
        #pragma unroll
        for (int r = 0; r < 4; ++r)
            d[wb * 4 + r] = fmaf(-2.0f, acc[wb][r], x2 + c2_s[wb * 16 + h * 4 + r]);

    /* exact row min across 16 regs + 4 lanes */
    float m1 = d[0];
    #pragma unroll
    for (int i = 1; i < 16; ++i) m1 = fminf(m1, d[i]);
    m1 = fminf(m1, __shfl_xor(m1, 16));
    m1 = fminf(m1, __shfl_xor(m1, 32));

    /* near-tie gate: >=2 candidates within 4e-4 of min (covers split-bf16 err ~1e-4) */
    float thr = m1 + 4e-4f;
    int cnt = 0;
    #pragma unroll
    for (int i = 0; i < 16; ++i) cnt += (d[i] < thr) ? 1 : 0;
    cnt += __shfl_xor(cnt, 16);
    cnt += __shfl_xor(cnt, 32);

    /* argmin: smallest word index among exact-min matches (np first-min rule) */
    int wsel = 9999;
    #pragma unroll
    for (int wb = 0; wb < 4; ++wb)
        #pragma unroll
        for (int r = 0; r < 4; ++r)
            if (d[wb * 4 + r] == m1) wsel = min(wsel, wb * 16 + h * 4 + r);
    wsel = min(wsel, __shfl_xor(wsel, 16));
    wsel = min(wsel, __shfl_xor(wsel, 32));

    /* softmax (m1 is the true row min -> no rescale ever) */
    float p[16];
    float sum = 0.f;
    #pragma unroll
    for (int i = 0; i < 16; ++i) {
        p[i] = __builtin_amdgcn_exp2f((m1 - d[i]) * TAU_K);
        sum += p[i];
    }
    sum += __shfl_xor(sum, 16);
    sum += __shfl_xor(sum, 32);
    float inv = __builtin_amdgcn_rcpf(sum);

    /* P -> bf16 -> per-wave LDS (padded stride 72: conflict-free, same-wave dep only) */
    #pragma unroll
    for (int wb = 0; wb < 4; ++wb) {
        unsigned int lo = (unsigned int)f2bf(p[wb * 4 + 0]) | ((unsigned int)f2bf(p[wb * 4 + 1]) << 16);
        unsigned int hi = (unsigned int)f2bf(p[wb * 4 + 2]) | ((unsigned int)f2bf(p[wb * 4 + 3]) << 16);
        uint2 pk; pk.x = lo; pk.y = hi;
        *(uint2*)&ps_s[wid][c][wb * 16 + h * 4] = pk;
    }
    /* B2-frags: row c, words kc*32 + 8h..+7 (compiler inserts lgkmcnt wait) */
    s16x8 pb0 = *(const s16x8*)&ps_s[wid][c][h * 8];
    s16x8 pb1 = *(const s16x8*)&ps_s[wid][c][32 + h * 8];

    /* 4 Z-MFMAs: Z[dim][row] = sum_w cb[w][dim] * P[w][row] */
    size_t rowoff = (size_t)(n0 + R) * DIMS + b * LWORD;
    #pragma unroll
    for (int mb = 0; mb < 2; ++mb) {
        f32x4 z = {0.f, 0.f, 0.f, 0.f};
        z = __builtin_amdgcn_mfma_f32_16x16x32_bf16(a2f[mb * 2 + 0], pb0, z, 0, 0, 0);
        z = __builtin_amdgcn_mfma_f32_16x16x32_bf16(a2f[mb * 2 + 1], pb1, z, 0, 0, 0);
        float4 v;
        v.x = z[0] * inv; v.y = z[1] * inv; v.z = z[2] * inv; v.w = z[3] * inv;
        *(float4*)(out + rowoff + mb * 16 + h * 4) = v;
    }

    /* idx (+ rare np-exact rescan) by the h==0 lane of each row */
    if (h == 0) {
        int wm = wsel;
        if (cnt >= 2) {
            float xr2[LWORD], sq[LWORD];
            #pragma unroll
            for (int l = 0; l < LWORD; ++l) { xr2[l] = x_s[R][l]; sq[l] = xr2[l] * xr2[l]; }
            float x2n = np_sum32(sq);
            float best = __builtin_inff();
            int wbest = 0;
            const float* Cb = cbT + (size_t)b * NWORDS * LWORD;
            for (int w2 = 0; w2 < NWORDS; ++w2) {
                const float* cw = Cb + (size_t)w2 * LWORD;
                double accd = 0.0;
                #pragma unroll
                for (int l = 0; l < LWORD; ++l)
                    accd = fma((double)xr2[l], (double)cw[l], accd);
                float xcf = (float)accd;
                float dnp;
                {
#pragma clang fp contract(off)
                    float s1 = x2n + c2_s[w2];
                    float s2 = 2.0f * xcf;
                    dnp = s1 - s2;
                }
                if (dnp < best) { best = dnp; wbest = w2; }
            }
            wm = wbest;
        }
        out[Z_ELEMS + (size_t)(n0 + R) * NBOOKS + b] = (float)wm;
    }
}

extern "C" void kernel_launch(void* const* d_in, const int* in_sizes, int n_in,
                              void* d_out, int out_size, void* d_ws, size_t ws_size,
                              hipStream_t stream) {
    const float* x = (const float*)d_in[0];
    const float* C = (const float*)d_in[1];
    float* out = (float*)d_out;
    char* ws = (char*)d_ws;
    float* cbT = (float*)(ws + CBT_OFF);
    float* c2T = (float*)(ws + C2T_OFF);
    unsigned short* chA = (unsigned short*)(ws + CHA_OFF);
    unsigned short* clA = (unsigned short*)(ws + CLA_OFF);
    unsigned short* a2A = (unsigned short*)(ws + A2_OFF);

    normC_kernel<<<32, 256, 0, stream>>>(C, cbT, c2T);
    fragC_kernel<<<128, 64, 0, stream>>>(cbT, chA, clA, a2A);
    softpq_mfma<<<32768, 256, 0, stream>>>(x, cbT, c2T, chA, clA, a2A, out);
}

// Round 4
// 229.014 us; speedup vs baseline: 1.7224x; 1.0455x over previous
//
#include <hip/hip_runtime.h>
#include <math.h>

#define NROWS   16384
#define NBOOKS  128
#define NWORDS  64
#define LWORD   32
#define DIMS    4096
#define TAU_K   14.4269504088896340736f   /* 10 * log2(e) */
#define Z_ELEMS 67108864ull               /* 16384*4096 */

typedef __attribute__((ext_vector_type(8))) short s16x8;
typedef __attribute__((ext_vector_type(4))) float f32x4;
typedef __attribute__((ext_vector_type(4))) unsigned int u32x4;

/* ws layout (bytes) */
#define CBT_OFF  0u           /* f32 [128][64][32] np-normalized codewords     */
#define C2T_OFF  1048576u     /* f32 [128][64]                                 */
#define CHA_OFF  1081344u     /* bf16 S-frags hi: [(b*4+wb)*64+lane][8]        */
#define CLA_OFF  1605632u     /* bf16 S-frags lo                               */
#define A2_OFF   2129920u     /* bf16 Z-frags:   [(b*4+mb*2+kc)*64+lane][8]    */
#define C2I_OFF  2654208u     /* f32x4 acc-init: [(b*4+wb)*64+lane] = -c2/2    */

__device__ __forceinline__ unsigned short f2bf(float f) {
    unsigned int u = __float_as_uint(f);
    unsigned int r = (u + 0x7FFFu + ((u >> 16) & 1u)) >> 16;   /* RNE */
    return (unsigned short)r;
}
__device__ __forceinline__ float bf2f(unsigned short s) {
    return __uint_as_float(((unsigned int)s) << 16);
}
__device__ __forceinline__ unsigned int cvtpk_bf16(float lo, float hi) {
    unsigned int r;
    asm("v_cvt_pk_bf16_f32 %0, %1, %2" : "=v"(r) : "v"(lo), "v"(hi));  /* RNE */
    return r;
}

/* numpy pairwise-sum replica for n=32 f32 (exact order, no contraction) */
__device__ __forceinline__ float np_sum32(const float* a) {
#pragma clang fp contract(off)
    float r0 = a[0], r1 = a[1], r2 = a[2], r3 = a[3];
    float r4 = a[4], r5 = a[5], r6 = a[6], r7 = a[7];
    r0 += a[8];  r1 += a[9];  r2 += a[10]; r3 += a[11];
    r4 += a[12]; r5 += a[13]; r6 += a[14]; r7 += a[15];
    r0 += a[16]; r1 += a[17]; r2 += a[18]; r3 += a[19];
    r4 += a[20]; r5 += a[21]; r6 += a[22]; r7 += a[23];
    r0 += a[24]; r1 += a[25]; r2 += a[26]; r3 += a[27];
    r4 += a[28]; r5 += a[29]; r6 += a[30]; r7 += a[31];
    return ((r0 + r1) + (r2 + r3)) + ((r4 + r5) + (r6 + r7));
}

/* ---------- kernel 1: np-exact per-book L2-normalize (verified) ---------- */
__global__ __launch_bounds__(256) void normC_kernel(const float* __restrict__ C,
                                                    float* __restrict__ cbT,
                                                    float* __restrict__ c2T) {
#pragma clang fp contract(off)
    int t = blockIdx.x * 256 + threadIdx.x;
    int w = t & (NWORDS - 1);
    int b = t >> 6;
    const float* src = C + (size_t)w * DIMS + b * LWORD;
    float v[LWORD];
    #pragma unroll
    for (int q = 0; q < 8; ++q)
        *(float4*)&v[4 * q] = *(const float4*)&src[4 * q];
    float sq[LWORD];
    #pragma unroll
    for (int l = 0; l < LWORD; ++l) sq[l] = v[l] * v[l];
    float nrm = fmaxf(sqrtf(np_sum32(sq)), 1e-12f);
    float cb[LWORD];
    #pragma unroll
    for (int l = 0; l < LWORD; ++l) cb[l] = v[l] / nrm;
    float sq2[LWORD];
    #pragma unroll
    for (int l = 0; l < LWORD; ++l) sq2[l] = cb[l] * cb[l];
    float c2 = np_sum32(sq2);
    float* dst = cbT + ((size_t)b * NWORDS + w) * LWORD;
    #pragma unroll
    for (int q = 0; q < 8; ++q)
        *(float4*)&dst[4 * q] = *(const float4*)&cb[4 * q];
    c2T[b * NWORDS + w] = c2;
}

/* ---------- kernel 1b: MFMA fragment-layout codeword arrays + c2 acc-init ---------- */
__global__ __launch_bounds__(64) void fragC_kernel(const float* __restrict__ cbT,
                                                   const float* __restrict__ c2T,
                                                   unsigned short* __restrict__ chA,
                                                   unsigned short* __restrict__ clA,
                                                   unsigned short* __restrict__ a2A,
                                                   float4* __restrict__ c2I) {
    int b = blockIdx.x;
    int l = threadIdx.x;
    int lr = l & 15, lh = l >> 4;
    #pragma unroll
    for (int wb = 0; wb < 4; ++wb) {
        size_t base = ((size_t)(b * 4 + wb) * 64 + l) * 8;
        #pragma unroll
        for (int i = 0; i < 8; ++i) {
            float f = cbT[((size_t)b * NWORDS + (wb * 16 + lr)) * LWORD + (lh * 8 + i)];
            unsigned short hh = f2bf(f);
            chA[base + i] = hh;
            clA[base + i] = f2bf(f - bf2f(hh));
        }
        float4 v;
        v.x = -0.5f * c2T[b * NWORDS + wb * 16 + lh * 4 + 0];
        v.y = -0.5f * c2T[b * NWORDS + wb * 16 + lh * 4 + 1];
        v.z = -0.5f * c2T[b * NWORDS + wb * 16 + lh * 4 + 2];
        v.w = -0.5f * c2T[b * NWORDS + wb * 16 + lh * 4 + 3];
        c2I[(size_t)(b * 4 + wb) * 64 + l] = v;
    }
    #pragma unroll
    for (int mb = 0; mb < 2; ++mb)
        #pragma unroll
        for (int kc = 0; kc < 2; ++kc) {
            size_t base = ((size_t)(b * 4 + mb * 2 + kc) * 64 + l) * 8;
            #pragma unroll
            for (int i = 0; i < 8; ++i)
                a2A[base + i] =
                    f2bf(cbT[((size_t)b * NWORDS + (kc * 32 + lh * 8 + i)) * LWORD + (mb * 16 + lr)]);
        }
}

/* ---------- kernel 2: 64 rows/wave, barrier-free, MFMA dist+softmax+Z+argmin ---------- */
__global__ __launch_bounds__(256, 2) void softpq_mfma(const float* __restrict__ x,
                                                      const float* __restrict__ cbT,
                                                      const float* __restrict__ c2T,
                                                      const unsigned short* __restrict__ chA,
                                                      const unsigned short* __restrict__ clA,
                                                      const unsigned short* __restrict__ a2A,
                                                      const float4* __restrict__ c2I,
                                                      float* __restrict__ out) {
    /* per-wave P buffer, double-buffered per group; stride 80 shorts = 160 B
       keeps every ds_read_b128 16B-aligned */
    __shared__ __align__(16) unsigned short ps_s[4][2][16][80];   /* 20480 B */

    int u = blockIdx.x;                      /* XCD-chunked: xcd k owns books 16k..16k+15 */
    int L = (u & 7) * 1024 + (u >> 3);
    int b  = L >> 6;
    int n0 = (L & 63) * 256;
    int t  = threadIdx.x;
    int lane = t & 63, wid = t >> 6;
    int h = lane >> 4, c = lane & 15;

    /* persistent per-wave fragments (L2-hot, coalesced 16B/lane) */
    const s16x8* chp = (const s16x8*)chA;
    const s16x8* clp = (const s16x8*)clA;
    const s16x8* a2p = (const s16x8*)a2A;
    s16x8 chf[4], clf[4], a2f[4];
    f32x4 ci[4];
    #pragma unroll
    for (int wb = 0; wb < 4; ++wb) {
        chf[wb] = chp[(size_t)(b * 4 + wb) * 64 + lane];
        clf[wb] = clp[(size_t)(b * 4 + wb) * 64 + lane];
        a2f[wb] = a2p[(size_t)(b * 4 + wb) * 64 + lane];
        float4 v = c2I[(size_t)(b * 4 + wb) * 64 + lane];
        f32x4 cv = {v.x, v.y, v.z, v.w};
        ci[wb] = cv;
    }

    #pragma unroll
    for (int g = 0; g < 4; ++g) {
        int R = wid * 64 + g * 16 + c;       /* local row */
        const float* xp = x + (size_t)(n0 + R) * DIMS + b * LWORD + h * 8;
        float4 va = *(const float4*)xp;
        float4 vb = *(const float4*)(xp + 4);
        float xf[8] = {va.x, va.y, va.z, va.w, vb.x, vb.y, vb.z, vb.w};

        /* split x into bf16 hi + bf16 residual via packed cvt */
        unsigned int xhu[4], xlu[4];
        #pragma unroll
        for (int j = 0; j < 4; ++j) {
            float f0 = xf[2 * j], f1 = xf[2 * j + 1];
            unsigned int ph = cvtpk_bf16(f0, f1);
            float h0 = __uint_as_float(ph << 16);
            float h1 = __uint_as_float(ph & 0xffff0000u);
            xhu[j] = ph;
            xlu[j] = cvtpk_bf16(f0 - h0, f1 - h1);
        }
        u32x4 thv = {xhu[0], xhu[1], xhu[2], xhu[3]};
        u32x4 tlv = {xlu[0], xlu[1], xlu[2], xlu[3]};
        s16x8 xhv = __builtin_bit_cast(s16x8, thv);
        s16x8 xlv = __builtin_bit_cast(s16x8, tlv);

        /* 12 S-MFMAs, acc init = -c2/2  ->  d' = -2*acc = c2 - 2*dot  (x2 drops
           out of softmax/argmin by shift invariance) */
        f32x4 acc[4];
        #pragma unroll
        for (int wb = 0; wb < 4; ++wb) {
            f32x4 a = ci[wb];
            a = __builtin_amdgcn_mfma_f32_16x16x32_bf16(chf[wb], xhv, a, 0, 0, 0);
            a = __builtin_amdgcn_mfma_f32_16x16x32_bf16(chf[wb], xlv, a, 0, 0, 0);
            a = __builtin_amdgcn_mfma_f32_16x16x32_bf16(clf[wb], xhv, a, 0, 0, 0);
            acc[wb] = a;
        }
        float d[16];
        #pragma unroll
        for (int wb = 0; wb < 4; ++wb)
            #pragma unroll
            for (int r = 0; r < 4; ++r)
                d[wb * 4 + r] = -2.0f * acc[wb][r];

        float m1 = d[0];
        #pragma unroll
        for (int i = 1; i < 16; ++i) m1 = fminf(m1, d[i]);
        m1 = fminf(m1, __shfl_xor(m1, 16));
        m1 = fminf(m1, __shfl_xor(m1, 32));

        float thr = m1 + 4e-4f;              /* covers split-bf16 err ~1e-4 */
        int cnt = 0;
        #pragma unroll
        for (int i = 0; i < 16; ++i) cnt += (d[i] < thr) ? 1 : 0;
        cnt += __shfl_xor(cnt, 16);
        cnt += __shfl_xor(cnt, 32);

        int wsel = 9999;
        #pragma unroll
        for (int wb = 0; wb < 4; ++wb)
            #pragma unroll
            for (int r = 0; r < 4; ++r)
                if (d[wb * 4 + r] == m1) wsel = min(wsel, wb * 16 + h * 4 + r);
        wsel = min(wsel, __shfl_xor(wsel, 16));
        wsel = min(wsel, __shfl_xor(wsel, 32));

        float m1t = m1 * TAU_K;
        float p[16];
        float sum = 0.f;
        #pragma unroll
        for (int i = 0; i < 16; ++i) {
            p[i] = __builtin_amdgcn_exp2f(fmaf(-TAU_K, d[i], m1t));
            sum += p[i];
        }
        sum += __shfl_xor(sum, 16);
        sum += __shfl_xor(sum, 32);
        float inv = __builtin_amdgcn_rcpf(sum);

        /* P -> bf16 -> per-wave LDS -> B-frags (same-wave dep, no barrier) */
        unsigned int pku[8];
        #pragma unroll
        for (int k = 0; k < 8; ++k) pku[k] = cvtpk_bf16(p[2 * k], p[2 * k + 1]);
        int gb = g & 1;
        #pragma unroll
        for (int wb = 0; wb < 4; ++wb) {
            uint2 w2; w2.x = pku[2 * wb]; w2.y = pku[2 * wb + 1];
            *(uint2*)&ps_s[wid][gb][c][wb * 16 + h * 4] = w2;
        }
        s16x8 pb0 = *(const s16x8*)&ps_s[wid][gb][c][h * 8];
        s16x8 pb1 = *(const s16x8*)&ps_s[wid][gb][c][32 + h * 8];

        float* zout = out + (size_t)(n0 + R) * DIMS + b * LWORD;
        #pragma unroll
        for (int mb = 0; mb < 2; ++mb) {
            f32x4 z = {0.f, 0.f, 0.f, 0.f};
            z = __builtin_amdgcn_mfma_f32_16x16x32_bf16(a2f[mb * 2 + 0], pb0, z, 0, 0, 0);
            z = __builtin_amdgcn_mfma_f32_16x16x32_bf16(a2f[mb * 2 + 1], pb1, z, 0, 0, 0);
            float4 v;
            v.x = z[0] * inv; v.y = z[1] * inv; v.z = z[2] * inv; v.w = z[3] * inv;
            *(float4*)(zout + mb * 16 + h * 4) = v;
        }

        if (h == 0) {
            int wm = wsel;
            if (cnt >= 2) {                  /* rare: replicate numpy-f32 exactly */
                const float* xrow = x + (size_t)(n0 + R) * DIMS + b * LWORD;
                float xr2[LWORD], sq[LWORD];
                #pragma unroll
                for (int q2 = 0; q2 < 8; ++q2)
                    *(float4*)&xr2[q2 * 4] = *(const float4*)(xrow + q2 * 4);
                #pragma unroll
                for (int l = 0; l < LWORD; ++l) sq[l] = xr2[l] * xr2[l];
                float x2n = np_sum32(sq);
                float best = __builtin_inff();
                int wbest = 0;
                const float* Cb = cbT + (size_t)b * NWORDS * LWORD;
                for (int w2 = 0; w2 < NWORDS; ++w2) {
                    const float* cw = Cb + (size_t)w2 * LWORD;
                    double accd = 0.0;
                    #pragma unroll
                    for (int l = 0; l < LWORD; ++l)
                        accd = fma((double)xr2[l], (double)cw[l], accd);
                    float xcf = (float)accd;
                    float dnp;
                    {
#pragma clang fp contract(off)
                        float s1 = x2n + c2T[b * NWORDS + w2];
                        float s2 = 2.0f * xcf;
                        dnp = s1 - s2;
                    }
                    if (dnp < best) { best = dnp; wbest = w2; }
                }
                wm = wbest;
            }
            out[Z_ELEMS + (size_t)(n0 + R) * NBOOKS + b] = (float)wm;
        }
    }
}

extern "C" void kernel_launch(void* const* d_in, const int* in_sizes, int n_in,
                              void* d_out, int out_size, void* d_ws, size_t ws_size,
                              hipStream_t stream) {
    const float* x = (const float*)d_in[0];
    const float* C = (const float*)d_in[1];
    float* out = (float*)d_out;
    char* ws = (char*)d_ws;
    float* cbT = (float*)(ws + CBT_OFF);
    float* c2T = (float*)(ws + C2T_OFF);
    unsigned short* chA = (unsigned short*)(ws + CHA_OFF);
    unsigned short* clA = (unsigned short*)(ws + CLA_OFF);
    unsigned short* a2A = (unsigned short*)(ws + A2_OFF);
    float4* c2I = (float4*)(ws + C2I_OFF);

    normC_kernel<<<32, 256, 0, stream>>>(C, cbT, c2T);
    fragC_kernel<<<128, 64, 0, stream>>>(cbT, c2T, chA, clA, a2A, c2I);
    softpq_mfma<<<8192, 256, 0, stream>>>(x, cbT, c2T, chA, clA, a2A, c2I, out);
}